// Round 3
// baseline (3943.196 us; speedup 1.0000x reference)
//
#include <hip/hip_runtime.h>

// LightGCN propagation: out = (h0+h1+h2+h3)/4, h_{l+1} = G @ h_l, COO input.
// Round-3 design: group edges by dst-BUCKET (128 users) instead of full CSR
// sort. 12.5K cell frontiers stay L2-resident during the scatter (round-2's
// 200K row frontiers caused 198MB write-allocate traffic). SpMM accumulates
// per-bucket rows in LDS via ds_add_f32 (stride-68 padding = conflict-free),
// one block per bucket, fused acc-update epilogue.

#define DIM 64
#define BUCKET_SHIFT 7          // 128 users per bucket
#define BUCKET_USERS 128
#define LSTRIDE 68              // LDS row stride (dwords): (4*dloc+lane)%32 covers all banks evenly
#define NSHARD 8
#define BIN_GRID 1024
#define BIN_BLK 256

// Histogram of (bucket, shard) cells. Must use the IDENTICAL grid + grid-stride
// mapping as scatter_cells so shard assignment matches.
__global__ void hist_cells(const int* __restrict__ dst, int* __restrict__ cnt, int n) {
    int i = blockIdx.x * blockDim.x + threadIdx.x;
    int stride = gridDim.x * blockDim.x;
    int shard = blockIdx.x & (NSHARD - 1);
    for (; i < n; i += stride) {
        int d = dst[i];
        atomicAdd(&cnt[((d >> BUCKET_SHIFT) << 3) | shard], 1);
    }
}

// Single-block exclusive scan of cell counts -> base (with sentinel) and cur.
__global__ void scan_cells(const int* __restrict__ cnt, int* __restrict__ base,
                           int* __restrict__ cur, int n) {
    __shared__ int sh[1024];
    int t = threadIdx.x;
    int C = (n + 1023) >> 10;
    int lo = t * C;
    int sum = 0;
    for (int j = 0; j < C; j++) {
        int idx = lo + j;
        if (idx < n) sum += cnt[idx];
    }
    sh[t] = sum;
    __syncthreads();
    for (int off = 1; off < 1024; off <<= 1) {
        int v = (t >= off) ? sh[t - off] : 0;
        __syncthreads();
        sh[t] += v;
        __syncthreads();
    }
    int run = (t == 0) ? 0 : sh[t - 1];
    for (int j = 0; j < C; j++) {
        int idx = lo + j;
        if (idx < n) {
            base[idx] = run;
            cur[idx] = run;
            run += cnt[idx];
        }
    }
    if (t == 1023) base[n] = sh[1023];
}

// Scatter edges into bucket-grouped bins. Frontier = 12.5K cells, L2-resident.
// Pack: x = src | (dst_local << 20), y = val bits. (n_users < 2^20)
__global__ void scatter_cells(const float* __restrict__ vals, const int* __restrict__ src,
                              const int* __restrict__ dst, int* __restrict__ cur,
                              int2* __restrict__ bins, int n) {
    int i = blockIdx.x * blockDim.x + threadIdx.x;
    int stride = gridDim.x * blockDim.x;
    int shard = blockIdx.x & (NSHARD - 1);
    for (; i < n; i += stride) {
        int d = dst[i];
        int cell = ((d >> BUCKET_SHIFT) << 3) | shard;
        int p = atomicAdd(&cur[cell], 1);
        bins[p] = make_int2(src[i] | ((d & (BUCKET_USERS - 1)) << 20),
                            __float_as_int(vals[i]));
    }
}

// One block per bucket; 8 waves; lane = feature dim. Each wave keeps 4 edges'
// 256B row-gathers in flight, accumulates into LDS with ds_add_f32.
// MODE 0: h_out = h; out = x0 + h        (layer 1)
// MODE 1: h_out = h; out += h            (layer 2)
// MODE 2: out = (out + h) * 0.25         (layer 3, h not stored)
template <int MODE>
__global__ __launch_bounds__(512)
void spmm_bucket(const int2* __restrict__ bins, const int* __restrict__ base,
                 const float* __restrict__ x, float* __restrict__ h_out,
                 const float* __restrict__ x0, float* __restrict__ out,
                 int n_users) {
    __shared__ float acc[BUCKET_USERS * LSTRIDE];
    int tid = threadIdx.x;
    int lane = tid & 63;
    int w = tid >> 6;                          // wave 0..7
    for (int i = tid; i < BUCKET_USERS * LSTRIDE; i += 512) acc[i] = 0.f;
    __syncthreads();

    int b = blockIdx.x;
    int start = base[b << 3];
    int end   = base[(b << 3) + 8];

    for (int i = start + w * 4; i < end; i += 32) {
        int2 ev0 = bins[i];
        int2 ev1 = (i + 1 < end) ? bins[i + 1] : make_int2(0, 0);
        int2 ev2 = (i + 2 < end) ? bins[i + 2] : make_int2(0, 0);
        int2 ev3 = (i + 3 < end) ? bins[i + 3] : make_int2(0, 0);
        float xv0 = x[(size_t)(ev0.x & 0xFFFFF) * DIM + lane];
        float xv1 = x[(size_t)(ev1.x & 0xFFFFF) * DIM + lane];
        float xv2 = x[(size_t)(ev2.x & 0xFFFFF) * DIM + lane];
        float xv3 = x[(size_t)(ev3.x & 0xFFFFF) * DIM + lane];
        atomicAdd(&acc[((unsigned)ev0.x >> 20) * LSTRIDE + lane], __int_as_float(ev0.y) * xv0);
        atomicAdd(&acc[((unsigned)ev1.x >> 20) * LSTRIDE + lane], __int_as_float(ev1.y) * xv1);
        atomicAdd(&acc[((unsigned)ev2.x >> 20) * LSTRIDE + lane], __int_as_float(ev2.y) * xv2);
        atomicAdd(&acc[((unsigned)ev3.x >> 20) * LSTRIDE + lane], __int_as_float(ev3.y) * xv3);
    }
    __syncthreads();

    // epilogue: write this bucket's rows once, fused with acc update
    int u0 = b << BUCKET_SHIFT;
    for (int r = w; r < BUCKET_USERS; r += 8) {
        int u = u0 + r;
        if (u >= n_users) break;               // u increases with r per wave
        float v = acc[r * LSTRIDE + lane];
        size_t g = (size_t)u * DIM + lane;
        if (MODE == 0) {
            h_out[g] = v;
            out[g] = x0[g] + v;
        } else if (MODE == 1) {
            h_out[g] = v;
            out[g] += v;
        } else {
            out[g] = (out[g] + v) * 0.25f;
        }
    }
}

extern "C" void kernel_launch(void* const* d_in, const int* in_sizes, int n_in,
                              void* d_out, int out_size, void* d_ws, size_t ws_size,
                              hipStream_t stream) {
    const float* user_emb  = (const float*)d_in[0];
    const float* edge_vals = (const float*)d_in[1];
    const int*   edge_src  = (const int*)d_in[2];
    const int*   edge_dst  = (const int*)d_in[3];
    float* out = (float*)d_out;

    const int n_users = in_sizes[0] / DIM;
    const int n_edges = in_sizes[1];
    const size_t nfloats = (size_t)n_users * DIM;
    const int nbucket = (n_users + BUCKET_USERS - 1) >> BUCKET_SHIFT;
    const int ncells = nbucket << 3;

    // workspace carve-up (16B-aligned chunks)
    char* ws = (char*)d_ws;
    float* h_a  = (float*)ws;  ws += ((nfloats * 4 + 15) & ~15ull);
    float* h_b  = (float*)ws;  ws += ((nfloats * 4 + 15) & ~15ull);
    int2*  bins = (int2*)ws;   ws += (((size_t)n_edges * 8 + 15) & ~15ull);
    int*   cnt  = (int*)ws;    ws += (((size_t)ncells * 4 + 15) & ~15ull);
    int*   bas  = (int*)ws;    ws += (((size_t)(ncells + 1) * 4 + 15) & ~15ull);
    int*   cur  = (int*)ws;

    // ---- build bucket-grouped bins (once per call, reused by all 3 layers) ----
    hipMemsetAsync(cnt, 0, (size_t)ncells * sizeof(int), stream);
    hist_cells<<<BIN_GRID, BIN_BLK, 0, stream>>>(edge_dst, cnt, n_edges);
    scan_cells<<<1, 1024, 0, stream>>>(cnt, bas, cur, ncells);
    scatter_cells<<<BIN_GRID, BIN_BLK, 0, stream>>>(edge_vals, edge_src, edge_dst,
                                                    cur, bins, n_edges);

    // ---- 3 propagation layers ----
    spmm_bucket<0><<<nbucket, 512, 0, stream>>>(bins, bas, user_emb, h_a, user_emb, out, n_users);
    spmm_bucket<1><<<nbucket, 512, 0, stream>>>(bins, bas, h_a, h_b, nullptr, out, n_users);
    spmm_bucket<2><<<nbucket, 512, 0, stream>>>(bins, bas, h_b, nullptr, nullptr, out, n_users);
}

// Round 4
// 872.299 us; speedup vs baseline: 4.5205x; 4.5205x over previous
//
#include <hip/hip_runtime.h>

// LightGCN propagation: out = (h0+h1+h2+h3)/4, h_{l+1} = G @ h_l, COO input.
// Round-4: round-2's register-accumulating CSR spmm (the fast one) + cheap
// two-level CSR build: (1) scatter into 12.5K bucket-shard cells (L2-resident
// frontier, kills round-2's 198MB write-allocate), (2) per-bucket counting
// sort into a contiguous CSR window. No 200K-row hist/scan, no LDS atomics
// in the spmm (round-3's 171G ds_add/s wall).

#define DIM 64
#define BUCKET_SHIFT 7          // 128 users per bucket
#define BUCKET_USERS 128
#define NSHARD 8
#define BIN_GRID 1024
#define BIN_BLK 256

// ---- phase A: histogram of (bucket, shard) cells ----
// Shard = blockIdx&7; must match scatter_cells' mapping exactly.
__global__ void hist_cells(const int* __restrict__ dst, int* __restrict__ cnt, int n) {
    int i = blockIdx.x * blockDim.x + threadIdx.x;
    int stride = gridDim.x * blockDim.x;
    int shard = blockIdx.x & (NSHARD - 1);
    for (; i < n; i += stride) {
        int d = dst[i];
        atomicAdd(&cnt[((d >> BUCKET_SHIFT) << 3) | shard], 1);
    }
}

// ---- phase B: single-block exclusive scan of ncells counts ----
__global__ void scan_cells(const int* __restrict__ cnt, int* __restrict__ base,
                           int* __restrict__ cur, int n) {
    __shared__ int sh[1024];
    int t = threadIdx.x;
    int C = (n + 1023) >> 10;
    int lo = t * C;
    int sum = 0;
    for (int j = 0; j < C; j++) {
        int idx = lo + j;
        if (idx < n) sum += cnt[idx];
    }
    sh[t] = sum;
    __syncthreads();
    for (int off = 1; off < 1024; off <<= 1) {
        int v = (t >= off) ? sh[t - off] : 0;
        __syncthreads();
        sh[t] += v;
        __syncthreads();
    }
    int run = (t == 0) ? 0 : sh[t - 1];
    for (int j = 0; j < C; j++) {
        int idx = lo + j;
        if (idx < n) {
            base[idx] = run;
            cur[idx] = run;
            run += cnt[idx];
        }
    }
    if (t == 1023) base[n] = sh[1023];
}

// ---- phase C: scatter edges into bucket-grouped bins ----
// Frontier = 12.5K cells (~800KB), L2-resident -> bins lines fill before
// eviction. Pack: x = src | (dst_local << 20)  (src < 2^20), y = val bits.
__global__ void scatter_cells(const float* __restrict__ vals, const int* __restrict__ src,
                              const int* __restrict__ dst, int* __restrict__ cur,
                              int2* __restrict__ bins, int n) {
    int i = blockIdx.x * blockDim.x + threadIdx.x;
    int stride = gridDim.x * blockDim.x;
    int shard = blockIdx.x & (NSHARD - 1);
    for (; i < n; i += stride) {
        int d = dst[i];
        int cell = ((d >> BUCKET_SHIFT) << 3) | shard;
        int p = atomicAdd(&cur[cell], 1);
        bins[p] = make_int2(src[i] | ((d & (BUCKET_USERS - 1)) << 20),
                            __float_as_int(vals[i]));
    }
}

// ---- phase D: per-bucket counting sort -> contiguous CSR window + row_end ----
__global__ __launch_bounds__(256)
void bucket_csr(const int2* __restrict__ bins, const int* __restrict__ base,
                int2* __restrict__ csr, int* __restrict__ row_end, int n_users) {
    __shared__ int cnt[BUCKET_USERS];
    __shared__ int pos[BUCKET_USERS];   // running write cursor (starts at excl prefix)
    int b = blockIdx.x;
    int t = threadIdx.x;
    for (int i = t; i < BUCKET_USERS; i += 256) cnt[i] = 0;
    __syncthreads();
    int s0 = base[b << 3];
    int s1 = base[(b << 3) + NSHARD];
    for (int i = s0 + t; i < s1; i += 256)
        atomicAdd(&cnt[((unsigned)bins[i].x) >> 20], 1);
    __syncthreads();
    if (t < 64) {
        int c0 = cnt[2 * t], c1 = cnt[2 * t + 1];
        int s = c0 + c1;
        for (int off = 1; off < 64; off <<= 1) {
            int v = __shfl_up(s, off, 64);
            if (t >= off) s += v;
        }
        int excl = s - (c0 + c1);           // exclusive prefix for row 2t
        pos[2 * t] = excl;
        pos[2 * t + 1] = excl + c0;
        int u0 = b << BUCKET_SHIFT;
        if (u0 + 2 * t < n_users)     row_end[u0 + 2 * t]     = s0 + excl + c0;
        if (u0 + 2 * t + 1 < n_users) row_end[u0 + 2 * t + 1] = s0 + excl + c0 + c1;
    }
    __syncthreads();
    for (int i = s0 + t; i < s1; i += 256) {
        int2 ev = bins[i];
        int p = atomicAdd(&pos[((unsigned)ev.x) >> 20], 1);
        csr[s0 + p] = make_int2(ev.x & 0xFFFFF, ev.y);
    }
}

// ---- spmm: one wave per dst row (round-2 structure) ----
// 4 lane-groups of 16 walk edges start+g, +4, ...; lane sl covers dims
// sl*4..sl*4+3 as float4; two shfl_xor steps reduce the groups.
// MODE 0: h_out = h; acc = x[row] + h   MODE 1: h_out = h; acc += h
// MODE 2: acc = (acc + h) * 0.25
template <int MODE>
__global__ __launch_bounds__(256)
void spmm_csr(const int2* __restrict__ edges, const int* __restrict__ row_end,
              const float* __restrict__ x, float* __restrict__ h_out,
              float* __restrict__ acc, int n_rows) {
    int row = blockIdx.x * (blockDim.x >> 6) + (threadIdx.x >> 6);
    if (row >= n_rows) return;
    int lane = threadIdx.x & 63;
    int g = lane >> 4;
    int sl = lane & 15;

    int start = (row == 0) ? 0 : row_end[row - 1];
    int end = row_end[row];

    float4 a = make_float4(0.f, 0.f, 0.f, 0.f);
    for (int e = start + g; e < end; e += 4) {
        int2 ev = edges[e];
        float v = __int_as_float(ev.y);
        const float4 xv = *(const float4*)&x[(size_t)ev.x * DIM + sl * 4];
        a.x += v * xv.x; a.y += v * xv.y; a.z += v * xv.z; a.w += v * xv.w;
    }
    a.x += __shfl_xor(a.x, 16, 64); a.y += __shfl_xor(a.y, 16, 64);
    a.z += __shfl_xor(a.z, 16, 64); a.w += __shfl_xor(a.w, 16, 64);
    a.x += __shfl_xor(a.x, 32, 64); a.y += __shfl_xor(a.y, 32, 64);
    a.z += __shfl_xor(a.z, 32, 64); a.w += __shfl_xor(a.w, 32, 64);

    size_t base = (size_t)row * DIM + sl * 4;
    if (MODE == 0) {
        if (g == 0) *(float4*)&h_out[base] = a;
        if (g == 1) {
            float4 x0 = *(const float4*)&x[base];
            x0.x += a.x; x0.y += a.y; x0.z += a.z; x0.w += a.w;
            *(float4*)&acc[base] = x0;
        }
    } else if (MODE == 1) {
        if (g == 0) *(float4*)&h_out[base] = a;
        if (g == 1) {
            float4 c = *(const float4*)&acc[base];
            c.x += a.x; c.y += a.y; c.z += a.z; c.w += a.w;
            *(float4*)&acc[base] = c;
        }
    } else {
        if (g == 0) {
            float4 c = *(const float4*)&acc[base];
            c.x = (c.x + a.x) * 0.25f; c.y = (c.y + a.y) * 0.25f;
            c.z = (c.z + a.z) * 0.25f; c.w = (c.w + a.w) * 0.25f;
            *(float4*)&acc[base] = c;
        }
    }
}

extern "C" void kernel_launch(void* const* d_in, const int* in_sizes, int n_in,
                              void* d_out, int out_size, void* d_ws, size_t ws_size,
                              hipStream_t stream) {
    const float* user_emb  = (const float*)d_in[0];
    const float* edge_vals = (const float*)d_in[1];
    const int*   edge_src  = (const int*)d_in[2];
    const int*   edge_dst  = (const int*)d_in[3];
    float* out = (float*)d_out;

    const int n_users = in_sizes[0] / DIM;
    const int n_edges = in_sizes[1];
    const size_t nfloats = (size_t)n_users * DIM;
    const int nbucket = (n_users + BUCKET_USERS - 1) >> BUCKET_SHIFT;
    const int ncells = nbucket << 3;

    // Workspace carve-up. h_b ALIASES the bins/cnt/base/cur region: those are
    // dead before spmm<1> first writes h_b. Footprint = 2*51.2 + 25.6 + 0.8 MB.
    char* ws = (char*)d_ws;
    float* h_a     = (float*)ws;  ws += nfloats * sizeof(float);
    int2*  csr     = (int2*)ws;   ws += (size_t)n_edges * sizeof(int2);
    int*   row_end = (int*)ws;    ws += (size_t)n_users * sizeof(int);
    char*  overlay = ws;
    float* h_b     = (float*)overlay;
    int2*  bins    = (int2*)overlay;            // dead after bucket_csr
    int*   cnt     = (int*)(overlay + (size_t)n_edges * sizeof(int2));
    int*   bas     = cnt + ncells;
    int*   cur     = bas + ncells + 4;          // +4: keep 16B alignment after sentinel

    // ---- build bucket-grouped CSR (once per call, reused by all 3 layers) ----
    hipMemsetAsync(cnt, 0, (size_t)ncells * sizeof(int), stream);
    hist_cells<<<BIN_GRID, BIN_BLK, 0, stream>>>(edge_dst, cnt, n_edges);
    scan_cells<<<1, 1024, 0, stream>>>(cnt, bas, cur, ncells);
    scatter_cells<<<BIN_GRID, BIN_BLK, 0, stream>>>(edge_vals, edge_src, edge_dst,
                                                    cur, bins, n_edges);
    bucket_csr<<<nbucket, 256, 0, stream>>>(bins, bas, csr, row_end, n_users);

    // ---- 3 propagation layers (atomic-free, register accumulate) ----
    const int nblk = (n_users + 3) / 4;         // 4 waves (rows) per 256-thr block
    spmm_csr<0><<<nblk, 256, 0, stream>>>(csr, row_end, user_emb, h_a, out, n_users);
    spmm_csr<1><<<nblk, 256, 0, stream>>>(csr, row_end, h_a, h_b, out, n_users);
    spmm_csr<2><<<nblk, 256, 0, stream>>>(csr, row_end, h_b, nullptr, out, n_users);
}

// Round 5
// 561.083 us; speedup vs baseline: 7.0278x; 1.5547x over previous
//
#include <hip/hip_runtime.h>

// LightGCN propagation: out = (h0+h1+h2+h3)/4, h_{l+1} = G @ h_l, COO input.
// Round-5:
//  (a) Build: run-based scatter with deterministic offsets (no contended
//      global atomics, coalesced run writes) -> bucket-grouped bins -> per-
//      bucket counting sort to CSR.  Round-4's scatter_cells lost 161us to
//      256-way cursor atomics + 32B-sector writebacks of scattered 8B stores.
//  (b) SpMM: gather operand in bf16 (128B/row vs 256B), f32 accumulate and
//      f32 acc updates. Halves the dominant gather traffic.

#define DIM 64
#define BUCKET_SHIFT 7          // 128 users per bucket
#define BUCKET_USERS 128
#define NBLK_P 256              // partition blocks for hist2d/scatter_runs
#define SCHUNK 12544            // >= ceil(E/NBLK_P) = 12500
#define MAXB 2048               // >= nbucket (1563); scan padding
typedef unsigned short u16;

__device__ inline u16 f2bf(float f) {
    unsigned u = __float_as_uint(f);
    u += 0x7fffu + ((u >> 16) & 1u);        // round-to-nearest-even
    return (u16)(u >> 16);
}
__device__ inline float bf2f(u16 h) { return __uint_as_float(((unsigned)h) << 16); }

// ---- f32 -> bf16 copy of user_emb (gather source for layer 1) ----
__global__ void conv_bf16(const float4* __restrict__ in, ushort4* __restrict__ out, int n4) {
    int i = blockIdx.x * blockDim.x + threadIdx.x;
    int stride = gridDim.x * blockDim.x;
    for (; i < n4; i += stride) {
        float4 v = in[i];
        ushort4 o;
        o.x = f2bf(v.x); o.y = f2bf(v.y); o.z = f2bf(v.z); o.w = f2bf(v.w);
        out[i] = o;
    }
}

// ---- per-(bucket, block) histogram: cnt2d[bucket*NBLK_P + blk] ----
__global__ __launch_bounds__(512)
void hist2d(const int* __restrict__ dst, int* __restrict__ cnt2d, int n_edges, int NB) {
    __shared__ int c[MAXB];
    int blk = blockIdx.x, t = threadIdx.x;
    int CH = (n_edges + NBLK_P - 1) / NBLK_P;
    int c0 = blk * CH, c1 = min(c0 + CH, n_edges);
    for (int i = t; i < NB; i += 512) c[i] = 0;
    __syncthreads();
    for (int i = c0 + t; i < c1; i += 512) atomicAdd(&c[dst[i] >> BUCKET_SHIFT], 1);
    __syncthreads();
    for (int i = t; i < NB; i += 512) cnt2d[i * NBLK_P + blk] = c[i];
}

// ---- per-bucket exclusive scan over blocks: one wave per bucket ----
__global__ void runstarts(const int* __restrict__ cnt2d, int* __restrict__ runst2d,
                          int* __restrict__ total, int NB) {
    int wid = (blockIdx.x * blockDim.x + threadIdx.x) >> 6;
    int lane = threadIdx.x & 63;
    if (wid >= NB) return;
    int carry = 0;
    for (int k = 0; k < NBLK_P; k += 64) {
        int cv = cnt2d[wid * NBLK_P + k + lane];
        int s = cv;
        for (int off = 1; off < 64; off <<= 1) {
            int v = __shfl_up(s, off, 64);
            if (lane >= off) s += v;
        }
        runst2d[wid * NBLK_P + k + lane] = carry + s - cv;
        carry += __shfl(s, 63, 64);
    }
    if (lane == 0) total[wid] = carry;
}

// ---- single-block exclusive scan of bucket totals -> base (+sentinel) ----
__global__ void scan_base(const int* __restrict__ cnt, int* __restrict__ base, int n) {
    __shared__ int sh[1024];
    int t = threadIdx.x;
    int C = (n + 1023) >> 10;
    int lo = t * C;
    int sum = 0;
    for (int j = 0; j < C; j++) { int idx = lo + j; if (idx < n) sum += cnt[idx]; }
    sh[t] = sum;
    __syncthreads();
    for (int off = 1; off < 1024; off <<= 1) {
        int v = (t >= off) ? sh[t - off] : 0;
        __syncthreads();
        sh[t] += v;
        __syncthreads();
    }
    int run = (t == 0) ? 0 : sh[t - 1];
    for (int j = 0; j < C; j++) {
        int idx = lo + j;
        if (idx < n) { base[idx] = run; run += cnt[idx]; }
    }
    if (t == 1023) base[n] = sh[1023];
}

// ---- scatter into bucket-grouped bins via LDS counting sort + run writes ----
// Deterministic global position: base[b] + runst2d[b][blk] + local_rank.
// Writeout walks slots in order -> coalesced full-line bins writes.
__global__ __launch_bounds__(512)
void scatter_runs(const float* __restrict__ vals, const int* __restrict__ src,
                  const int* __restrict__ dst, const int* __restrict__ base,
                  const int* __restrict__ runst2d, int2* __restrict__ bins,
                  int NB, int n_edges) {
    __shared__ int2 stage[SCHUNK];
    __shared__ u16 sbk[SCHUNK];
    __shared__ int s_start[MAXB];
    __shared__ int s_cur[MAXB];
    __shared__ int s_gb[MAXB];
    __shared__ int s_tmp[512];
    int blk = blockIdx.x, t = threadIdx.x;
    int CH = (n_edges + NBLK_P - 1) / NBLK_P;
    int c0 = blk * CH, c1 = min(c0 + CH, n_edges);

    for (int i = t; i < NB; i += 512) s_start[i] = 0;
    __syncthreads();
    for (int i = c0 + t; i < c1; i += 512) atomicAdd(&s_start[dst[i] >> BUCKET_SHIFT], 1);
    __syncthreads();

    // block exclusive scan over NB counts (NPT=MAXB/512 per thread)
    const int NPT = MAXB / 512;
    int lo = t * NPT, run = 0, loc[NPT];
#pragma unroll
    for (int j = 0; j < NPT; j++) {
        int idx = lo + j;
        int cv = (idx < NB) ? s_start[idx] : 0;
        loc[j] = run; run += cv;
    }
    s_tmp[t] = run;
    __syncthreads();
    for (int off = 1; off < 512; off <<= 1) {
        int v = (t >= off) ? s_tmp[t - off] : 0;
        __syncthreads();
        s_tmp[t] += v;
        __syncthreads();
    }
    int excl = (t == 0) ? 0 : s_tmp[t - 1];
    int totloc = s_tmp[511];
#pragma unroll
    for (int j = 0; j < NPT; j++) {
        int idx = lo + j;
        if (idx < NB) { int st = excl + loc[j]; s_start[idx] = st; s_cur[idx] = st; }
    }
    for (int i = t; i < NB; i += 512) s_gb[i] = base[i] + runst2d[i * NBLK_P + blk];
    __syncthreads();

    // place edges into LDS staging at their local sorted position
    for (int i = c0 + t; i < c1; i += 512) {
        int d = dst[i];
        int b = d >> BUCKET_SHIFT;
        int p = atomicAdd(&s_cur[b], 1);
        stage[p] = make_int2(src[i] | ((d & (BUCKET_USERS - 1)) << 20),
                             __float_as_int(vals[i]));
        sbk[p] = (u16)b;
    }
    __syncthreads();

    // ordered writeout: consecutive slots -> consecutive bins addresses
    for (int i = t; i < totloc; i += 512) {
        int b = sbk[i];
        bins[s_gb[b] + (i - s_start[b])] = stage[i];
    }
}

// ---- per-bucket counting sort -> contiguous CSR window + row_end ----
__global__ __launch_bounds__(256)
void bucket_csr(const int2* __restrict__ bins, const int* __restrict__ base,
                int2* __restrict__ csr, int* __restrict__ row_end, int n_users) {
    __shared__ int cnt[BUCKET_USERS];
    __shared__ int pos[BUCKET_USERS];
    int b = blockIdx.x;
    int t = threadIdx.x;
    for (int i = t; i < BUCKET_USERS; i += 256) cnt[i] = 0;
    __syncthreads();
    int s0 = base[b];
    int s1 = base[b + 1];
    for (int i = s0 + t; i < s1; i += 256)
        atomicAdd(&cnt[((unsigned)bins[i].x) >> 20], 1);
    __syncthreads();
    if (t < 64) {
        int c0 = cnt[2 * t], c1 = cnt[2 * t + 1];
        int s = c0 + c1;
        for (int off = 1; off < 64; off <<= 1) {
            int v = __shfl_up(s, off, 64);
            if (t >= off) s += v;
        }
        int excl = s - (c0 + c1);
        pos[2 * t] = excl;
        pos[2 * t + 1] = excl + c0;
        int u0 = b << BUCKET_SHIFT;
        if (u0 + 2 * t < n_users)     row_end[u0 + 2 * t]     = s0 + excl + c0;
        if (u0 + 2 * t + 1 < n_users) row_end[u0 + 2 * t + 1] = s0 + excl + c0 + c1;
    }
    __syncthreads();
    for (int i = s0 + t; i < s1; i += 256) {
        int2 ev = bins[i];
        int p = atomicAdd(&pos[((unsigned)ev.x) >> 20], 1);
        csr[s0 + p] = make_int2(ev.x & 0xFFFFF, ev.y);
    }
}

// ---- spmm: one wave per dst row; bf16 gather, f32 accumulate ----
// 4 lane-groups of 16 walk edges start+g, +4...; lane sl covers dims sl*4..+3.
// MODE 0: hb_out = bf16(h); acc = x0[row] + h
// MODE 1: hb_out = bf16(h); acc += h
// MODE 2: acc = (acc + h) * 0.25
template <int MODE>
__global__ __launch_bounds__(256)
void spmm_bf(const int2* __restrict__ edges, const int* __restrict__ row_end,
             const u16* __restrict__ xb, u16* __restrict__ hb_out,
             const float* __restrict__ x0, float* __restrict__ acc, int n_rows) {
    int row = blockIdx.x * 4 + (threadIdx.x >> 6);
    if (row >= n_rows) return;
    int lane = threadIdx.x & 63;
    int g = lane >> 4;
    int sl = lane & 15;

    int start = (row == 0) ? 0 : row_end[row - 1];
    int end = row_end[row];

    float4 a = make_float4(0.f, 0.f, 0.f, 0.f);
    for (int e = start + g; e < end; e += 4) {
        int2 ev = edges[e];
        float v = __int_as_float(ev.y);
        ushort4 xv = *(const ushort4*)&xb[(size_t)(ev.x & 0xFFFFF) * DIM + sl * 4];
        a.x += v * bf2f(xv.x); a.y += v * bf2f(xv.y);
        a.z += v * bf2f(xv.z); a.w += v * bf2f(xv.w);
    }
    a.x += __shfl_xor(a.x, 16, 64); a.y += __shfl_xor(a.y, 16, 64);
    a.z += __shfl_xor(a.z, 16, 64); a.w += __shfl_xor(a.w, 16, 64);
    a.x += __shfl_xor(a.x, 32, 64); a.y += __shfl_xor(a.y, 32, 64);
    a.z += __shfl_xor(a.z, 32, 64); a.w += __shfl_xor(a.w, 32, 64);

    size_t gb = (size_t)row * DIM + sl * 4;
    if (MODE == 0) {
        if (g == 0) {
            ushort4 o; o.x = f2bf(a.x); o.y = f2bf(a.y); o.z = f2bf(a.z); o.w = f2bf(a.w);
            *(ushort4*)&hb_out[gb] = o;
        }
        if (g == 1) {
            float4 x0v = *(const float4*)&x0[gb];
            x0v.x += a.x; x0v.y += a.y; x0v.z += a.z; x0v.w += a.w;
            *(float4*)&acc[gb] = x0v;
        }
    } else if (MODE == 1) {
        if (g == 0) {
            ushort4 o; o.x = f2bf(a.x); o.y = f2bf(a.y); o.z = f2bf(a.z); o.w = f2bf(a.w);
            *(ushort4*)&hb_out[gb] = o;
        }
        if (g == 1) {
            float4 c = *(const float4*)&acc[gb];
            c.x += a.x; c.y += a.y; c.z += a.z; c.w += a.w;
            *(float4*)&acc[gb] = c;
        }
    } else {
        if (g == 0) {
            float4 c = *(const float4*)&acc[gb];
            c.x = (c.x + a.x) * 0.25f; c.y = (c.y + a.y) * 0.25f;
            c.z = (c.z + a.z) * 0.25f; c.w = (c.w + a.w) * 0.25f;
            *(float4*)&acc[gb] = c;
        }
    }
}

extern "C" void kernel_launch(void* const* d_in, const int* in_sizes, int n_in,
                              void* d_out, int out_size, void* d_ws, size_t ws_size,
                              hipStream_t stream) {
    const float* user_emb  = (const float*)d_in[0];
    const float* edge_vals = (const float*)d_in[1];
    const int*   edge_src  = (const int*)d_in[2];
    const int*   edge_dst  = (const int*)d_in[3];
    float* out = (float*)d_out;

    const int n_users = in_sizes[0] / DIM;
    const int n_edges = in_sizes[1];
    const size_t nfloats = (size_t)n_users * DIM;
    const int nbucket = (n_users + BUCKET_USERS - 1) >> BUCKET_SHIFT;   // 1563

    // Workspace carve-up (256B-aligned). bins aliases hb_a: bins is dead
    // after bucket_csr, hb_a first written by spmm<0>. Total ~103 MB.
    auto align = [](size_t x) { return (x + 255) & ~(size_t)255; };
    char* ws = (char*)d_ws;
    int2* csr      = (int2*)ws;  ws += align((size_t)n_edges * sizeof(int2));
    int*  row_end  = (int*)ws;   ws += align((size_t)n_users * sizeof(int));
    u16*  xb0      = (u16*)ws;   ws += align(nfloats * sizeof(u16));
    char* overlayA = ws;         ws += align((size_t)n_edges * sizeof(int2));
    u16*  hb_a     = (u16*)overlayA;
    int2* bins     = (int2*)overlayA;
    u16*  hb_b     = (u16*)ws;   ws += align(nfloats * sizeof(u16));
    int*  cnt2d    = (int*)ws;   ws += align((size_t)nbucket * NBLK_P * sizeof(int));
    int*  runst2d  = (int*)ws;   ws += align((size_t)nbucket * NBLK_P * sizeof(int));
    int*  total    = (int*)ws;   ws += align((size_t)nbucket * sizeof(int));
    int*  base     = (int*)ws;

    // ---- bf16 copy of user_emb (layer-1 gather source) ----
    conv_bf16<<<2048, 256, 0, stream>>>((const float4*)user_emb, (ushort4*)xb0,
                                        (int)(nfloats / 4));

    // ---- build bucket-grouped CSR (deterministic, contention-free) ----
    hist2d<<<NBLK_P, 512, 0, stream>>>(edge_dst, cnt2d, n_edges, nbucket);
    runstarts<<<(nbucket + 3) / 4, 256, 0, stream>>>(cnt2d, runst2d, total, nbucket);
    scan_base<<<1, 1024, 0, stream>>>(total, base, nbucket);
    scatter_runs<<<NBLK_P, 512, 0, stream>>>(edge_vals, edge_src, edge_dst,
                                             base, runst2d, bins, nbucket, n_edges);
    bucket_csr<<<nbucket, 256, 0, stream>>>(bins, base, csr, row_end, n_users);

    // ---- 3 propagation layers (bf16 gather, f32 acc) ----
    const int nblk = (n_users + 3) / 4;
    spmm_bf<0><<<nblk, 256, 0, stream>>>(csr, row_end, xb0, hb_a, user_emb, out, n_users);
    spmm_bf<1><<<nblk, 256, 0, stream>>>(csr, row_end, hb_a, hb_b, nullptr, out, n_users);
    spmm_bf<2><<<nblk, 256, 0, stream>>>(csr, row_end, hb_b, nullptr, nullptr, out, n_users);
}

// Round 6
// 514.092 us; speedup vs baseline: 7.6702x; 1.0914x over previous
//
#include <hip/hip_runtime.h>

// LightGCN propagation: out = (h0+h1+h2+h3)/4, h_{l+1} = G @ h_l, COO input.
// Round-6 (build identical to round-5; spmm restructured):
//  (a) gather loop unrolled 4x guarded -> 16 edges in flight per wave; an
//      avg row (deg~16) completes in ONE latency round-trip (was 4 serial).
//  (b) no f32 acc streaming: layers 1-2 write bf16 h only; layer-3 epilogue
//      computes out = (x0 + h1 + h2 + h3)/4 from x0(f32)+h1,h2(bf16)+h3(reg).
//      Removes the acc read-modify-write chain + ~120MB net traffic.

#define DIM 64
#define BUCKET_SHIFT 7          // 128 users per bucket
#define BUCKET_USERS 128
#define NBLK_P 256              // partition blocks for hist2d/scatter_runs
#define SCHUNK 12544            // >= ceil(E/NBLK_P) = 12500
#define MAXB 2048               // >= nbucket (1563); scan padding
typedef unsigned short u16;

__device__ inline u16 f2bf(float f) {
    unsigned u = __float_as_uint(f);
    u += 0x7fffu + ((u >> 16) & 1u);        // round-to-nearest-even
    return (u16)(u >> 16);
}
__device__ inline float bf2f(u16 h) { return __uint_as_float(((unsigned)h) << 16); }

// ---- f32 -> bf16 copy of user_emb (gather source for layer 1) ----
__global__ void conv_bf16(const float4* __restrict__ in, ushort4* __restrict__ out, int n4) {
    int i = blockIdx.x * blockDim.x + threadIdx.x;
    int stride = gridDim.x * blockDim.x;
    for (; i < n4; i += stride) {
        float4 v = in[i];
        ushort4 o;
        o.x = f2bf(v.x); o.y = f2bf(v.y); o.z = f2bf(v.z); o.w = f2bf(v.w);
        out[i] = o;
    }
}

// ---- per-(bucket, block) histogram: cnt2d[bucket*NBLK_P + blk] ----
__global__ __launch_bounds__(512)
void hist2d(const int* __restrict__ dst, int* __restrict__ cnt2d, int n_edges, int NB) {
    __shared__ int c[MAXB];
    int blk = blockIdx.x, t = threadIdx.x;
    int CH = (n_edges + NBLK_P - 1) / NBLK_P;
    int c0 = blk * CH, c1 = min(c0 + CH, n_edges);
    for (int i = t; i < NB; i += 512) c[i] = 0;
    __syncthreads();
    for (int i = c0 + t; i < c1; i += 512) atomicAdd(&c[dst[i] >> BUCKET_SHIFT], 1);
    __syncthreads();
    for (int i = t; i < NB; i += 512) cnt2d[i * NBLK_P + blk] = c[i];
}

// ---- per-bucket exclusive scan over blocks: one wave per bucket ----
__global__ void runstarts(const int* __restrict__ cnt2d, int* __restrict__ runst2d,
                          int* __restrict__ total, int NB) {
    int wid = (blockIdx.x * blockDim.x + threadIdx.x) >> 6;
    int lane = threadIdx.x & 63;
    if (wid >= NB) return;
    int carry = 0;
    for (int k = 0; k < NBLK_P; k += 64) {
        int cv = cnt2d[wid * NBLK_P + k + lane];
        int s = cv;
        for (int off = 1; off < 64; off <<= 1) {
            int v = __shfl_up(s, off, 64);
            if (lane >= off) s += v;
        }
        runst2d[wid * NBLK_P + k + lane] = carry + s - cv;
        carry += __shfl(s, 63, 64);
    }
    if (lane == 0) total[wid] = carry;
}

// ---- single-block exclusive scan of bucket totals -> base (+sentinel) ----
__global__ void scan_base(const int* __restrict__ cnt, int* __restrict__ base, int n) {
    __shared__ int sh[1024];
    int t = threadIdx.x;
    int C = (n + 1023) >> 10;
    int lo = t * C;
    int sum = 0;
    for (int j = 0; j < C; j++) { int idx = lo + j; if (idx < n) sum += cnt[idx]; }
    sh[t] = sum;
    __syncthreads();
    for (int off = 1; off < 1024; off <<= 1) {
        int v = (t >= off) ? sh[t - off] : 0;
        __syncthreads();
        sh[t] += v;
        __syncthreads();
    }
    int run = (t == 0) ? 0 : sh[t - 1];
    for (int j = 0; j < C; j++) {
        int idx = lo + j;
        if (idx < n) { base[idx] = run; run += cnt[idx]; }
    }
    if (t == 1023) base[n] = sh[1023];
}

// ---- scatter into bucket-grouped bins via LDS counting sort + run writes ----
__global__ __launch_bounds__(512)
void scatter_runs(const float* __restrict__ vals, const int* __restrict__ src,
                  const int* __restrict__ dst, const int* __restrict__ base,
                  const int* __restrict__ runst2d, int2* __restrict__ bins,
                  int NB, int n_edges) {
    __shared__ int2 stage[SCHUNK];
    __shared__ u16 sbk[SCHUNK];
    __shared__ int s_start[MAXB];
    __shared__ int s_cur[MAXB];
    __shared__ int s_gb[MAXB];
    __shared__ int s_tmp[512];
    int blk = blockIdx.x, t = threadIdx.x;
    int CH = (n_edges + NBLK_P - 1) / NBLK_P;
    int c0 = blk * CH, c1 = min(c0 + CH, n_edges);

    for (int i = t; i < NB; i += 512) s_start[i] = 0;
    __syncthreads();
    for (int i = c0 + t; i < c1; i += 512) atomicAdd(&s_start[dst[i] >> BUCKET_SHIFT], 1);
    __syncthreads();

    const int NPT = MAXB / 512;
    int lo = t * NPT, run = 0, loc[NPT];
#pragma unroll
    for (int j = 0; j < NPT; j++) {
        int idx = lo + j;
        int cv = (idx < NB) ? s_start[idx] : 0;
        loc[j] = run; run += cv;
    }
    s_tmp[t] = run;
    __syncthreads();
    for (int off = 1; off < 512; off <<= 1) {
        int v = (t >= off) ? s_tmp[t - off] : 0;
        __syncthreads();
        s_tmp[t] += v;
        __syncthreads();
    }
    int excl = (t == 0) ? 0 : s_tmp[t - 1];
    int totloc = s_tmp[511];
#pragma unroll
    for (int j = 0; j < NPT; j++) {
        int idx = lo + j;
        if (idx < NB) { int st = excl + loc[j]; s_start[idx] = st; s_cur[idx] = st; }
    }
    for (int i = t; i < NB; i += 512) s_gb[i] = base[i] + runst2d[i * NBLK_P + blk];
    __syncthreads();

    for (int i = c0 + t; i < c1; i += 512) {
        int d = dst[i];
        int b = d >> BUCKET_SHIFT;
        int p = atomicAdd(&s_cur[b], 1);
        stage[p] = make_int2(src[i] | ((d & (BUCKET_USERS - 1)) << 20),
                             __float_as_int(vals[i]));
        sbk[p] = (u16)b;
    }
    __syncthreads();

    for (int i = t; i < totloc; i += 512) {
        int b = sbk[i];
        bins[s_gb[b] + (i - s_start[b])] = stage[i];
    }
}

// ---- per-bucket counting sort -> contiguous CSR window + row_end ----
__global__ __launch_bounds__(256)
void bucket_csr(const int2* __restrict__ bins, const int* __restrict__ base,
                int2* __restrict__ csr, int* __restrict__ row_end, int n_users) {
    __shared__ int cnt[BUCKET_USERS];
    __shared__ int pos[BUCKET_USERS];
    int b = blockIdx.x;
    int t = threadIdx.x;
    for (int i = t; i < BUCKET_USERS; i += 256) cnt[i] = 0;
    __syncthreads();
    int s0 = base[b];
    int s1 = base[b + 1];
    for (int i = s0 + t; i < s1; i += 256)
        atomicAdd(&cnt[((unsigned)bins[i].x) >> 20], 1);
    __syncthreads();
    if (t < 64) {
        int c0 = cnt[2 * t], c1 = cnt[2 * t + 1];
        int s = c0 + c1;
        for (int off = 1; off < 64; off <<= 1) {
            int v = __shfl_up(s, off, 64);
            if (t >= off) s += v;
        }
        int excl = s - (c0 + c1);
        pos[2 * t] = excl;
        pos[2 * t + 1] = excl + c0;
        int u0 = b << BUCKET_SHIFT;
        if (u0 + 2 * t < n_users)     row_end[u0 + 2 * t]     = s0 + excl + c0;
        if (u0 + 2 * t + 1 < n_users) row_end[u0 + 2 * t + 1] = s0 + excl + c0 + c1;
    }
    __syncthreads();
    for (int i = s0 + t; i < s1; i += 256) {
        int2 ev = bins[i];
        int p = atomicAdd(&pos[((unsigned)ev.x) >> 20], 1);
        csr[s0 + p] = make_int2(ev.x & 0xFFFFF, ev.y);
    }
}

// ---- spmm: one wave per dst row; bf16 gather; 4x-unrolled (16 edges in
// flight). MODE 0/1: hb_out = bf16(h), nothing else.
// MODE 2: out = (x0 + h1 + h2 + h_reg) * 0.25  (h3 never stored).
template <int MODE>
__global__ __launch_bounds__(256)
void spmm_bf(const int2* __restrict__ edges, const int* __restrict__ row_end,
             const u16* __restrict__ xb, u16* __restrict__ hb_out,
             const float* __restrict__ x0, const u16* __restrict__ h1,
             const u16* __restrict__ h2, float* __restrict__ outp, int n_rows) {
    int row = blockIdx.x * 4 + (threadIdx.x >> 6);
    if (row >= n_rows) return;
    int lane = threadIdx.x & 63;
    int g = lane >> 4;
    int sl = lane & 15;

    int start = (row == 0) ? 0 : row_end[row - 1];
    int end = row_end[row];

    float4 a = make_float4(0.f, 0.f, 0.f, 0.f);
    for (int e = start + g; e < end; e += 16) {
        // issue all edge loads first, then all (independent) gathers
        int2 ev0 = edges[e];
        int2 ev1 = make_int2(0, 0), ev2 = make_int2(0, 0), ev3 = make_int2(0, 0);
        ushort4 xv1 = make_ushort4(0, 0, 0, 0), xv2 = xv1, xv3 = xv1;
        bool g1 = (e + 4 < end), g2 = (e + 8 < end), g3 = (e + 12 < end);
        if (g1) ev1 = edges[e + 4];
        if (g2) ev2 = edges[e + 8];
        if (g3) ev3 = edges[e + 12];
        ushort4 xv0 = *(const ushort4*)&xb[(size_t)(ev0.x & 0xFFFFF) * DIM + sl * 4];
        if (g1) xv1 = *(const ushort4*)&xb[(size_t)(ev1.x & 0xFFFFF) * DIM + sl * 4];
        if (g2) xv2 = *(const ushort4*)&xb[(size_t)(ev2.x & 0xFFFFF) * DIM + sl * 4];
        if (g3) xv3 = *(const ushort4*)&xb[(size_t)(ev3.x & 0xFFFFF) * DIM + sl * 4];
        float v0 = __int_as_float(ev0.y), v1 = __int_as_float(ev1.y);
        float v2 = __int_as_float(ev2.y), v3 = __int_as_float(ev3.y);
        a.x += v0 * bf2f(xv0.x); a.y += v0 * bf2f(xv0.y);
        a.z += v0 * bf2f(xv0.z); a.w += v0 * bf2f(xv0.w);
        a.x += v1 * bf2f(xv1.x); a.y += v1 * bf2f(xv1.y);
        a.z += v1 * bf2f(xv1.z); a.w += v1 * bf2f(xv1.w);
        a.x += v2 * bf2f(xv2.x); a.y += v2 * bf2f(xv2.y);
        a.z += v2 * bf2f(xv2.z); a.w += v2 * bf2f(xv2.w);
        a.x += v3 * bf2f(xv3.x); a.y += v3 * bf2f(xv3.y);
        a.z += v3 * bf2f(xv3.z); a.w += v3 * bf2f(xv3.w);
    }
    a.x += __shfl_xor(a.x, 16, 64); a.y += __shfl_xor(a.y, 16, 64);
    a.z += __shfl_xor(a.z, 16, 64); a.w += __shfl_xor(a.w, 16, 64);
    a.x += __shfl_xor(a.x, 32, 64); a.y += __shfl_xor(a.y, 32, 64);
    a.z += __shfl_xor(a.z, 32, 64); a.w += __shfl_xor(a.w, 32, 64);

    size_t gb = (size_t)row * DIM + sl * 4;
    if (MODE != 2) {
        if (g == 0) {
            ushort4 o;
            o.x = f2bf(a.x); o.y = f2bf(a.y); o.z = f2bf(a.z); o.w = f2bf(a.w);
            *(ushort4*)&hb_out[gb] = o;
        }
    } else {
        if (g == 0) {
            float4 x0v = *(const float4*)&x0[gb];
            ushort4 h1v = *(const ushort4*)&h1[gb];
            ushort4 h2v = *(const ushort4*)&h2[gb];
            float4 o;
            o.x = (x0v.x + bf2f(h1v.x) + bf2f(h2v.x) + a.x) * 0.25f;
            o.y = (x0v.y + bf2f(h1v.y) + bf2f(h2v.y) + a.y) * 0.25f;
            o.z = (x0v.z + bf2f(h1v.z) + bf2f(h2v.z) + a.z) * 0.25f;
            o.w = (x0v.w + bf2f(h1v.w) + bf2f(h2v.w) + a.w) * 0.25f;
            *(float4*)&outp[gb] = o;
        }
    }
}

extern "C" void kernel_launch(void* const* d_in, const int* in_sizes, int n_in,
                              void* d_out, int out_size, void* d_ws, size_t ws_size,
                              hipStream_t stream) {
    const float* user_emb  = (const float*)d_in[0];
    const float* edge_vals = (const float*)d_in[1];
    const int*   edge_src  = (const int*)d_in[2];
    const int*   edge_dst  = (const int*)d_in[3];
    float* out = (float*)d_out;

    const int n_users = in_sizes[0] / DIM;
    const int n_edges = in_sizes[1];
    const size_t nfloats = (size_t)n_users * DIM;
    const int nbucket = (n_users + BUCKET_USERS - 1) >> BUCKET_SHIFT;   // 1563

    // Workspace carve-up (256B-aligned). bins aliases hb_a: bins dead after
    // bucket_csr; hb_a first written by spmm<0>, read again by spmm<2>.
    auto align = [](size_t x) { return (x + 255) & ~(size_t)255; };
    char* ws = (char*)d_ws;
    int2* csr      = (int2*)ws;  ws += align((size_t)n_edges * sizeof(int2));
    int*  row_end  = (int*)ws;   ws += align((size_t)n_users * sizeof(int));
    u16*  xb0      = (u16*)ws;   ws += align(nfloats * sizeof(u16));
    char* overlayA = ws;         ws += align((size_t)n_edges * sizeof(int2));
    u16*  hb_a     = (u16*)overlayA;
    int2* bins     = (int2*)overlayA;
    u16*  hb_b     = (u16*)ws;   ws += align(nfloats * sizeof(u16));
    int*  cnt2d    = (int*)ws;   ws += align((size_t)nbucket * NBLK_P * sizeof(int));
    int*  runst2d  = (int*)ws;   ws += align((size_t)nbucket * NBLK_P * sizeof(int));
    int*  total    = (int*)ws;   ws += align((size_t)nbucket * sizeof(int));
    int*  base     = (int*)ws;

    // ---- bf16 copy of user_emb (layer-1 gather source) ----
    conv_bf16<<<2048, 256, 0, stream>>>((const float4*)user_emb, (ushort4*)xb0,
                                        (int)(nfloats / 4));

    // ---- build bucket-grouped CSR (deterministic, contention-free) ----
    hist2d<<<NBLK_P, 512, 0, stream>>>(edge_dst, cnt2d, n_edges, nbucket);
    runstarts<<<(nbucket + 3) / 4, 256, 0, stream>>>(cnt2d, runst2d, total, nbucket);
    scan_base<<<1, 1024, 0, stream>>>(total, base, nbucket);
    scatter_runs<<<NBLK_P, 512, 0, stream>>>(edge_vals, edge_src, edge_dst,
                                             base, runst2d, bins, nbucket, n_edges);
    bucket_csr<<<nbucket, 256, 0, stream>>>(bins, base, csr, row_end, n_users);

    // ---- 3 propagation layers (bf16 gather, no acc streaming) ----
    const int nblk = (n_users + 3) / 4;
    spmm_bf<0><<<nblk, 256, 0, stream>>>(csr, row_end, xb0, hb_a,
                                         nullptr, nullptr, nullptr, nullptr, n_users);
    spmm_bf<1><<<nblk, 256, 0, stream>>>(csr, row_end, hb_a, hb_b,
                                         nullptr, nullptr, nullptr, nullptr, n_users);
    spmm_bf<2><<<nblk, 256, 0, stream>>>(csr, row_end, hb_b, nullptr,
                                         user_emb, hb_a, hb_b, out, n_users);
}